// Round 9
// baseline (132.070 us; speedup 1.0000x reference)
//
#include <hip/hip_runtime.h>

typedef __attribute__((ext_vector_type(4))) float f32x4;
typedef __attribute__((ext_vector_type(8))) short s16x8;
typedef __attribute__((ext_vector_type(4))) short s16x4;
typedef __attribute__((ext_vector_type(2))) unsigned int u32x2;

#define LSEQ 2048
#define NB   8
#define CH   8            // k-tiles (of 64) per split-K chunk
#define UPB  80           // work units per batch
#define NUNIT 640

// log2(e) folded into Q scale and mask-penalty scale: softmax runs in the
// log2 domain (exp2 is the native v_exp_f32).
#define QSCALE   0.180336880f    // 0.125 * log2(e)
#define PENSCALE 1.8033688e8f    // 1.25e8 * log2(e)

// workspace byte offsets
#define OFF_QB    0x000000u   // bf16 [8][2048][64]  (Q pre-scaled by QSCALE)
#define OFF_KB    0x200000u   // bf16 [8][2048][64]
#define OFF_VTB   0x400000u   // bf16 [8][64][2048]  (V transposed)
#define OFF_PEN   0x600000u   // f32  [8][2048]      ((mask-1)*PENSCALE)
#define OFF_KREL  0x610000u   // bf16 [48][64]       (rows>=33 zero)
#define OFF_OPART 0x620000u   // f32  [640][64][64]
#define OFF_ML    0x1020000u  // f32  [640][64][2]

__device__ __forceinline__ unsigned short f2bf(float f) {
    union { float f; unsigned int u; } v; v.f = f;
    unsigned int u = v.u;
    return (unsigned short)((u + 0x7fffu + ((u >> 16) & 1u)) >> 16);
}

__device__ __forceinline__ float bf2f(unsigned short b) {
    union { unsigned int u; float f; } v; v.u = ((unsigned int)b) << 16;
    return v.f;
}

// pack 2 f32 -> u32 of 2 bf16 (RNE), single instruction
__device__ __forceinline__ unsigned int cvtpk(float lo, float hi) {
    unsigned int r;
    asm("v_cvt_pk_bf16_f32 %0, %1, %2" : "=v"(r) : "v"(lo), "v"(hi));
    return r;
}

// ---------------- convert / transpose pre-pass ----------------
__global__ __launch_bounds__(256)
void convert_kernel(const float* __restrict__ Q, const float* __restrict__ K,
                    const float* __restrict__ V, const float* __restrict__ Msk,
                    const float* __restrict__ Krel, char* __restrict__ ws)
{
    const int tid = threadIdx.x;
    const int bid = blockIdx.x;
    unsigned short* Qb  = (unsigned short*)(ws + OFF_QB);
    unsigned short* Kb  = (unsigned short*)(ws + OFF_KB);
    unsigned short* VTb = (unsigned short*)(ws + OFF_VTB);
    float*          pen = (float*)(ws + OFF_PEN);
    unsigned short* Krb = (unsigned short*)(ws + OFF_KREL);

    if (bid < 1024) {                       // Q -> bf16, scaled
        int base = bid * 1024 + tid * 4;
        f32x4 q4 = *(const f32x4*)(Q + base);
        s16x4 o;
        o.x = (short)f2bf(q4.x * QSCALE); o.y = (short)f2bf(q4.y * QSCALE);
        o.z = (short)f2bf(q4.z * QSCALE); o.w = (short)f2bf(q4.w * QSCALE);
        *(s16x4*)(Qb + base) = o;
    } else if (bid < 2048) {                // K -> bf16
        int base = (bid - 1024) * 1024 + tid * 4;
        f32x4 k4 = *(const f32x4*)(K + base);
        s16x4 o;
        o.x = (short)f2bf(k4.x); o.y = (short)f2bf(k4.y);
        o.z = (short)f2bf(k4.z); o.w = (short)f2bf(k4.w);
        *(s16x4*)(Kb + base) = o;
    } else if (bid < 2304) {                // V transpose (64x64 tiles) -> bf16
        __shared__ unsigned short tileT[64][72];
        int tile = bid - 2048;
        int b = tile >> 5, k0 = (tile & 31) << 6;
        #pragma unroll
        for (int rep = 0; rep < 4; ++rep) {
            int idx = tid + rep * 256;
            int kr = idx >> 4, dc0 = (idx & 15) << 2;
            f32x4 v4 = *(const f32x4*)(V + (size_t)(b * 2048 + k0 + kr) * 64 + dc0);
            tileT[dc0 + 0][kr] = f2bf(v4.x);
            tileT[dc0 + 1][kr] = f2bf(v4.y);
            tileT[dc0 + 2][kr] = f2bf(v4.z);
            tileT[dc0 + 3][kr] = f2bf(v4.w);
        }
        __syncthreads();
        #pragma unroll
        for (int rep = 0; rep < 2; ++rep) {
            int idx = tid + rep * 256;
            int d = idx >> 3, ch = idx & 7;
            *(s16x8*)(VTb + (size_t)(b * 64 + d) * 2048 + k0 + ch * 8) =
                *(const s16x8*)&tileT[d][ch * 8];
        }
    } else if (bid < 2312) {                // mask -> additive penalty (log2 dom)
        int i0 = (bid - 2304) * 2048 + tid * 8;
        f32x4 m0 = *(const f32x4*)(Msk + i0);
        f32x4 m1 = *(const f32x4*)(Msk + i0 + 4);
        f32x4 p0 = (m0 - 1.0f) * PENSCALE;
        f32x4 p1 = (m1 - 1.0f) * PENSCALE;
        *(f32x4*)(pen + i0) = p0;
        *(f32x4*)(pen + i0 + 4) = p1;
    } else {                                // Krel -> bf16, padded to 48 rows
        for (int g = tid; g < 768; g += 256) {
            int e = g * 4, row = e >> 6, col = e & 63;
            s16x4 o;
            if (row < 33) {
                f32x4 v = *(const f32x4*)(Krel + row * 64 + col);
                o.x = (short)f2bf(v.x); o.y = (short)f2bf(v.y);
                o.z = (short)f2bf(v.z); o.w = (short)f2bf(v.w);
            } else {
                o.x = 0; o.y = 0; o.z = 0; o.w = 0;
            }
            *(s16x4*)(Krb + row * 64 + col) = o;
        }
    }
}

// ---------------- main flash-attention (split-K, L2-direct frags) ----------------
// LDS (bytes): P per-wave 4x2048 @0; drel f32[4][16][20] @8192; Vrel f32[17][72] @13312
#define LDS_P    0
#define LDS_DREL 8192
#define LDS_VREL 13312
#define LDS_TOT  18208

__device__ __forceinline__ void near_bias(f32x4& sv, const f32x4& pv, int cc,
                                          int k0, int g0, int q,
                                          const float* drel) {
#pragma unroll
    for (int r = 0; r < 4; ++r) {
        int kk = k0 + cc * 16 + 4 * g0 + r;
        int dlt = q - kk;
        int idx = dlt < 16 ? dlt : 16;
        idx = idx < 0 ? 0 : idx;
        float bb = drel[idx];
        float v = sv[r] + bb + pv[r];
        sv[r] = (dlt < 0) ? -1e30f : v;
    }
}

__global__ __launch_bounds__(256, 4)
void attn_main(const float* __restrict__ Vrel_g, float* __restrict__ Out,
               char* __restrict__ ws)
{
    __shared__ __align__(16) char lds[LDS_TOT];
    const int tid  = threadIdx.x;
    const int wv   = tid >> 6;
    const int lane = tid & 63;
    const int g0   = lane >> 4;
    const int qh   = lane & 15;

    // XCD-aware bijective swizzle: 640 units = 8 XCDs x 80 (one batch each).
    // Round-robin dispatch -> XCD x runs units [80x, 80x+80) = batch x only,
    // so its K/V working set (1 MB bf16) is L2-resident. Bijection: correctness
    // is mapping-independent.
    int u = (blockIdx.x & 7) * UPB + (blockIdx.x >> 3);
    int b = u / UPB;
    int u2 = u - b * UPB;
    int t, chunk, nck;
    if (u2 < 8)       { t = u2;               chunk = 0;          nck = 1; }
    else if (u2 < 24) { t = 8  + (u2 - 8) / 2;  chunk = (u2 - 8) & 1;  nck = 2; }
    else if (u2 < 48) { t = 16 + (u2 - 24) / 3; chunk = (u2 - 24) % 3; nck = 3; }
    else              { t = 24 + (u2 - 48) / 4; chunk = (u2 - 48) & 3; nck = 4; }
    const int q0   = t << 6;
    const int q0w  = q0 + wv * 16;
    const int q    = q0w + qh;
    const int ck0  = chunk * CH;
    const int ckend = min(ck0 + CH, t + 1);
    const bool is_final = (nck == 1);

    const unsigned short* Qb  = (const unsigned short*)(ws + OFF_QB);
    const unsigned short* Kb  = (const unsigned short*)(ws + OFF_KB);
    const unsigned short* VTb = (const unsigned short*)(ws + OFF_VTB);
    const float*          pen = (const float*)(ws + OFF_PEN);
    const unsigned short* Krb = (const unsigned short*)(ws + OFF_KREL);

    // Q fragments (hoisted); q-row = lane&15
    const size_t qrow = (size_t)(b * 2048 + q) * 64;
    s16x8 qf0 = *(const s16x8*)(Qb + qrow + 0 * 32 + g0 * 8);
    s16x8 qf1 = *(const s16x8*)(Qb + qrow + 1 * 32 + g0 * 8);

    // drel (relative-key dots) via MFMA: Krel rows 16..31 and 32 (per-wave LDS)
    {
        s16x8 a10 = *(const s16x8*)(Krb + (16 + qh) * 64 + 0 * 32 + g0 * 8);
        s16x8 a11 = *(const s16x8*)(Krb + (16 + qh) * 64 + 1 * 32 + g0 * 8);
        s16x8 a20 = *(const s16x8*)(Krb + (32 + qh) * 64 + 0 * 32 + g0 * 8);
        s16x8 a21 = *(const s16x8*)(Krb + (32 + qh) * 64 + 1 * 32 + g0 * 8);
        f32x4 z = {0.f, 0.f, 0.f, 0.f};
        f32x4 d1 = __builtin_amdgcn_mfma_f32_16x16x32_bf16(a10, qf0, z, 0, 0, 0);
        d1 = __builtin_amdgcn_mfma_f32_16x16x32_bf16(a11, qf1, d1, 0, 0, 0);
        f32x4 d2 = __builtin_amdgcn_mfma_f32_16x16x32_bf16(a20, qf0, z, 0, 0, 0);
        d2 = __builtin_amdgcn_mfma_f32_16x16x32_bf16(a21, qf1, d2, 0, 0, 0);
        float* drel = (float*)(lds + LDS_DREL) + wv * 320 + qh * 20;
        drel[4 * g0 + 0] = d1.x; drel[4 * g0 + 1] = d1.y;
        drel[4 * g0 + 2] = d1.z; drel[4 * g0 + 3] = d1.w;
        if (g0 == 0) drel[16] = d2.x;     // drel[q][32]
    }
    asm volatile("" ::: "memory");        // order drel writes vs reads below
    const float* drelT = (const float*)(lds + LDS_DREL) + wv * 320 + qh * 20;
    float bias32 = drelT[16];             // same-wave LDS readback

    // Vrel rows 0..16 staged f32 (shared across waves -> one barrier)
    {
        float* vr = (float*)(lds + LDS_VREL);
        for (int i = tid; i < 17 * 16; i += 256) {
            int row = i >> 4, c4 = (i & 15) << 2;
            *(f32x4*)(vr + row * 72 + c4) = *(const f32x4*)(Vrel_g + row * 64 + c4);
        }
    }
    __syncthreads();   // the ONLY block-wide barrier

    f32x4 o0 = {0,0,0,0}, o1 = {0,0,0,0}, o2 = {0,0,0,0}, o3 = {0,0,0,0};
    float mprev = -1e30f, lsum = 0.f;

    char* PL  = lds + LDS_P + wv * 2048;
    const int swzq = (qh & 7) << 4;
    const float* vrel = (const float*)(lds + LDS_VREL);

    // L2-direct fragment bases (verified equal to the former swizzled-LDS bytes):
    //  K  frag(cc,h): Kb [(b*2048 + k0 + 16*cc + qh)*64 + 32*h + 8*g0], 16B
    //  V^T frag(dg,h): VTb[(b*64 + 16*dg + qh)*2048 + k0 + 32*h + 8*g0], 16B
    const unsigned short* kfb = Kb  + (size_t)(b * 2048 + qh) * 64 + g0 * 8;
    const unsigned short* vfb = VTb + (size_t)(b * 64 + qh) * 2048 + g0 * 8;

    for (int kt = ck0; kt < ckend; ++kt) {
        const int k0 = kt << 6;
        if (k0 > q0w + 15) continue;      // fully-masked tile for this wave

        const unsigned short* kf = kfb + (size_t)k0 * 64;
        // ---- S^T = K_tile . Q^T (frags straight from L2) ----
        f32x4 s0, s1, s2, s3;
        {
            f32x4 z = {0,0,0,0};
            s16x8 a0 = *(const s16x8*)(kf + 0 * 1024 + 0);
            s16x8 a1 = *(const s16x8*)(kf + 0 * 1024 + 32);
            s16x8 a2 = *(const s16x8*)(kf + 1 * 1024 + 0);
            s16x8 a3 = *(const s16x8*)(kf + 1 * 1024 + 32);
            s0 = __builtin_amdgcn_mfma_f32_16x16x32_bf16(a0, qf0, z, 0, 0, 0);
            s0 = __builtin_amdgcn_mfma_f32_16x16x32_bf16(a1, qf1, s0, 0, 0, 0);
            a0 = *(const s16x8*)(kf + 2 * 1024 + 0);
            a1 = *(const s16x8*)(kf + 2 * 1024 + 32);
            s1 = __builtin_amdgcn_mfma_f32_16x16x32_bf16(a2, qf0, z, 0, 0, 0);
            s1 = __builtin_amdgcn_mfma_f32_16x16x32_bf16(a3, qf1, s1, 0, 0, 0);
            a2 = *(const s16x8*)(kf + 3 * 1024 + 0);
            a3 = *(const s16x8*)(kf + 3 * 1024 + 32);
            s2 = __builtin_amdgcn_mfma_f32_16x16x32_bf16(a0, qf0, z, 0, 0, 0);
            s2 = __builtin_amdgcn_mfma_f32_16x16x32_bf16(a1, qf1, s2, 0, 0, 0);
            s3 = __builtin_amdgcn_mfma_f32_16x16x32_bf16(a2, qf0, z, 0, 0, 0);
            s3 = __builtin_amdgcn_mfma_f32_16x16x32_bf16(a3, qf1, s3, 0, 0, 0);
        }
        // ---- bias + mask penalty (pen from L2) ----
        const float* penb = pen + b * 2048 + k0 + 4 * g0;
        f32x4 pn0 = *(const f32x4*)(penb + 0);
        f32x4 pn1 = *(const f32x4*)(penb + 16);
        f32x4 pn2 = *(const f32x4*)(penb + 32);
        f32x4 pn3 = *(const f32x4*)(penb + 48);
        const bool near = (k0 + 79 >= q0w);
        if (!near) {
            s0 += pn0 + bias32; s1 += pn1 + bias32;
            s2 += pn2 + bias32; s3 += pn3 + bias32;
        } else {
            near_bias(s0, pn0, 0, k0, g0, q, drelT);
            near_bias(s1, pn1, 1, k0, g0, q, drelT);
            near_bias(s2, pn2, 2, k0, g0, q, drelT);
            near_bias(s3, pn3, 3, k0, g0, q, drelT);
        }
        // ---- online softmax, log2 domain ----
        float mt = fmaxf(fmaxf(fmaxf(s0.x, s0.y), fmaxf(s0.z, s0.w)),
                  fmaxf(fmaxf(fmaxf(s1.x, s1.y), fmaxf(s1.z, s1.w)),
                  fmaxf(fmaxf(fmaxf(s2.x, s2.y), fmaxf(s2.z, s2.w)),
                        fmaxf(fmaxf(s3.x, s3.y), fmaxf(s3.z, s3.w)))));
        mt = fmaxf(mt, __shfl_xor(mt, 16));
        mt = fmaxf(mt, __shfl_xor(mt, 32));
        float mnew = fmaxf(mprev, mt);
        float fsc = __builtin_amdgcn_exp2f(mprev - mnew);
        s0.x = __builtin_amdgcn_exp2f(s0.x - mnew); s0.y = __builtin_amdgcn_exp2f(s0.y - mnew);
        s0.z = __builtin_amdgcn_exp2f(s0.z - mnew); s0.w = __builtin_amdgcn_exp2f(s0.w - mnew);
        s1.x = __builtin_amdgcn_exp2f(s1.x - mnew); s1.y = __builtin_amdgcn_exp2f(s1.y - mnew);
        s1.z = __builtin_amdgcn_exp2f(s1.z - mnew); s1.w = __builtin_amdgcn_exp2f(s1.w - mnew);
        s2.x = __builtin_amdgcn_exp2f(s2.x - mnew); s2.y = __builtin_amdgcn_exp2f(s2.y - mnew);
        s2.z = __builtin_amdgcn_exp2f(s2.z - mnew); s2.w = __builtin_amdgcn_exp2f(s2.w - mnew);
        s3.x = __builtin_amdgcn_exp2f(s3.x - mnew); s3.y = __builtin_amdgcn_exp2f(s3.y - mnew);
        s3.z = __builtin_amdgcn_exp2f(s3.z - mnew); s3.w = __builtin_amdgcn_exp2f(s3.w - mnew);
        float rs = (s0.x + s0.y + s0.z + s0.w) + (s1.x + s1.y + s1.z + s1.w)
                 + (s2.x + s2.y + s2.z + s2.w) + (s3.x + s3.y + s3.z + s3.w);
        rs += __shfl_xor(rs, 16);
        rs += __shfl_xor(rs, 32);
        lsum = lsum * fsc + rs;
        mprev = mnew;
        o0 *= fsc; o1 *= fsc; o2 *= fsc; o3 *= fsc;

        // ---- P -> bf16 via v_cvt_pk_bf16_f32 -> per-wave LDS (swizzled) ----
        {
            u32x2 pk;
            pk.x = cvtpk(s0.x, s0.y); pk.y = cvtpk(s0.z, s0.w);
            *(u32x2*)(PL + qh * 128 + ((0  + 8 * g0) ^ swzq)) = pk;
            pk.x = cvtpk(s1.x, s1.y); pk.y = cvtpk(s1.z, s1.w);
            *(u32x2*)(PL + qh * 128 + ((32 + 8 * g0) ^ swzq)) = pk;
            pk.x = cvtpk(s2.x, s2.y); pk.y = cvtpk(s2.z, s2.w);
            *(u32x2*)(PL + qh * 128 + ((64 + 8 * g0) ^ swzq)) = pk;
            pk.x = cvtpk(s3.x, s3.y); pk.y = cvtpk(s3.z, s3.w);
            *(u32x2*)(PL + qh * 128 + ((96 + 8 * g0) ^ swzq)) = pk;
        }
        asm volatile("" ::: "memory");   // P stores precede P reads
        // ---- O^T += V^T . P^T (V frags straight from L2) ----
        {
            const int b0 = (16 * g0) ^ swzq;
            const int b1 = (64 + 16 * g0) ^ swzq;
            s16x8 bP0 = *(const s16x8*)(PL + qh * 128 + b0);
            s16x8 bP1 = *(const s16x8*)(PL + qh * 128 + b1);
            asm volatile("" ::: "memory");
            const unsigned short* vf = vfb + k0;
            s16x8 v0 = *(const s16x8*)(vf + 0 * 32768 + 0);
            s16x8 v1 = *(const s16x8*)(vf + 0 * 32768 + 32);
            s16x8 v2 = *(const s16x8*)(vf + 1 * 32768 + 0);
            s16x8 v3 = *(const s16x8*)(vf + 1 * 32768 + 32);
            o0 = __builtin_amdgcn_mfma_f32_16x16x32_bf16(v0, bP0, o0, 0, 0, 0);
            o0 = __builtin_amdgcn_mfma_f32_16x16x32_bf16(v1, bP1, o0, 0, 0, 0);
            v0 = *(const s16x8*)(vf + 2 * 32768 + 0);
            v1 = *(const s16x8*)(vf + 2 * 32768 + 32);
            o1 = __builtin_amdgcn_mfma_f32_16x16x32_bf16(v2, bP0, o1, 0, 0, 0);
            o1 = __builtin_amdgcn_mfma_f32_16x16x32_bf16(v3, bP1, o1, 0, 0, 0);
            v2 = *(const s16x8*)(vf + 3 * 32768 + 0);
            v3 = *(const s16x8*)(vf + 3 * 32768 + 32);
            o2 = __builtin_amdgcn_mfma_f32_16x16x32_bf16(v0, bP0, o2, 0, 0, 0);
            o2 = __builtin_amdgcn_mfma_f32_16x16x32_bf16(v1, bP1, o2, 0, 0, 0);
            o3 = __builtin_amdgcn_mfma_f32_16x16x32_bf16(v2, bP0, o3, 0, 0, 0);
            o3 = __builtin_amdgcn_mfma_f32_16x16x32_bf16(v3, bP1, o3, 0, 0, 0);
        }
        // ---- near-diagonal relative-value recombination (all d) ----
        if (near) {
            const int kql = q - k0;
            #pragma unroll
            for (int dlt = 0; dlt <= 16; ++dlt) {
                int kkl = kql - dlt;
                if (kkl >= 0 && kkl < 64) {
                    float p = bf2f(*(const unsigned short*)
                                   (PL + qh * 128 + ((2 * kkl) ^ swzq)));
                    const float* vrow = vrel + (16 - dlt) * 72 + 4 * g0;
                    o0 += p * *(const f32x4*)(vrow + 0);
                    o1 += p * *(const f32x4*)(vrow + 16);
                    o2 += p * *(const f32x4*)(vrow + 32);
                    o3 += p * *(const f32x4*)(vrow + 48);
                }
            }
        }
    }

    // ---- epilogue ----
    if (is_final) {
        float inv = 1.f / lsum;
        float* op = Out + (size_t)(b * 2048 + q) * 64 + 4 * g0;
        *(f32x4*)(op + 0)  = o0 * inv;
        *(f32x4*)(op + 16) = o1 * inv;
        *(f32x4*)(op + 32) = o2 * inv;
        *(f32x4*)(op + 48) = o3 * inv;
    } else {
        float* op = (float*)(ws + OFF_OPART) + (size_t)u * 4096 + (wv * 16 + qh) * 64 + 4 * g0;
        *(f32x4*)(op + 0)  = o0;
        *(f32x4*)(op + 16) = o1;
        *(f32x4*)(op + 32) = o2;
        *(f32x4*)(op + 48) = o3;
        if (g0 == 0) {
            float* ml = (float*)(ws + OFF_ML) + (size_t)u * 128 + (wv * 16 + qh) * 2;
            ml[0] = mprev; ml[1] = lsum;
        }
    }
}

// ---------------- split-K combine ----------------
__global__ __launch_bounds__(256)
void combine_kernel(float* __restrict__ Out, const char* __restrict__ ws)
{
    int bid = blockIdx.x;          // 192 = 8 batches x 24 q-tiles (t=8..31)
    int b = bid / 24;
    int t = 8 + bid % 24;
    int nck = t / 8 + 1;
    int S;
    if (t < 16)      S = 8 + 2 * (t - 8);
    else if (t < 24) S = 24 + 3 * (t - 16);
    else             S = 48 + 4 * (t - 24);
    int ubase = b * UPB + S;
    int tid = threadIdx.x;
    int qloc = tid >> 2;
    int d0 = (tid & 3) << 4;
    const float* mlb = (const float*)(ws + OFF_ML);
    const float* opb = (const float*)(ws + OFF_OPART);

    float m[4], l[4];
    float M = -1e30f;
    #pragma unroll
    for (int i = 0; i < 4; ++i) {
        if (i < nck) {
            const float* ml = mlb + (size_t)(ubase + i) * 128 + qloc * 2;
            m[i] = ml[0]; l[i] = ml[1];
            M = fmaxf(M, m[i]);
        }
    }
    float L = 0.f;
    float coef[4];
    #pragma unroll
    for (int i = 0; i < 4; ++i) {
        if (i < nck) { coef[i] = __builtin_amdgcn_exp2f(m[i] - M); L += l[i] * coef[i]; }
    }
    f32x4 a0 = {0,0,0,0}, a1 = {0,0,0,0}, a2 = {0,0,0,0}, a3 = {0,0,0,0};
    #pragma unroll
    for (int i = 0; i < 4; ++i) {
        if (i < nck) {
            const float* op = opb + (size_t)(ubase + i) * 4096 + qloc * 64 + d0;
            a0 += coef[i] * *(const f32x4*)(op + 0);
            a1 += coef[i] * *(const f32x4*)(op + 4);
            a2 += coef[i] * *(const f32x4*)(op + 8);
            a3 += coef[i] * *(const f32x4*)(op + 12);
        }
    }
    float inv = 1.f / L;
    float* oo = Out + (size_t)(b * 2048 + t * 64 + qloc) * 64 + d0;
    *(f32x4*)(oo + 0)  = a0 * inv;
    *(f32x4*)(oo + 4)  = a1 * inv;
    *(f32x4*)(oo + 8)  = a2 * inv;
    *(f32x4*)(oo + 12) = a3 * inv;
}

extern "C" void kernel_launch(void* const* d_in, const int* in_sizes, int n_in,
                              void* d_out, int out_size, void* d_ws, size_t ws_size,
                              hipStream_t stream) {
    (void)in_sizes; (void)n_in; (void)out_size; (void)ws_size;
    const float* Q    = (const float*)d_in[0];
    const float* K    = (const float*)d_in[1];
    const float* V    = (const float*)d_in[2];
    const float* Msk  = (const float*)d_in[3];
    const float* Krel = (const float*)d_in[4];
    const float* Vrel = (const float*)d_in[5];
    float* Out = (float*)d_out;
    char* ws = (char*)d_ws;

    convert_kernel<<<2313, 256, 0, stream>>>(Q, K, V, Msk, Krel, ws);
    attn_main<<<NUNIT, 256, 0, stream>>>(Vrel, Out, ws);
    combine_kernel<<<192, 256, 0, stream>>>(Out, ws);
}

// Round 10
// 108.052 us; speedup vs baseline: 1.2223x; 1.2223x over previous
//
#include <hip/hip_runtime.h>

typedef __attribute__((ext_vector_type(4))) float f32x4;
typedef __attribute__((ext_vector_type(8))) short s16x8;
typedef __attribute__((ext_vector_type(4))) short s16x4;
typedef __attribute__((ext_vector_type(2))) unsigned int u32x2;

#define LSEQ 2048
#define NB   8
#define CH   4            // k-tiles (of 64) per split-K chunk
#define UPB  144          // work units per batch (CH=4, t=0..31)
#define NUNIT 1152        // 8 * 144, = 8 XCDs x 144

// log2(e) folded into Q scale and mask-penalty scale: softmax in log2 domain.
#define QSCALE   0.180336880f    // 0.125 * log2(e)
#define PENSCALE 1.8033688e8f    // 1.25e8 * log2(e)

// workspace byte offsets
#define OFF_QB    0x000000u   // bf16 [8][2048][64]  (Q pre-scaled by QSCALE)
#define OFF_KB    0x200000u   // bf16 [8][2048][64]
#define OFF_VTB   0x400000u   // bf16 [8][64][2048]  (V transposed)
#define OFF_PEN   0x600000u   // f32  [8][2048]      ((mask-1)*PENSCALE)
#define OFF_KREL  0x610000u   // bf16 [48][64]       (rows>=33 zero)
#define OFF_OPART 0x620000u   // f32  [1152][64][64]
#define OFF_ML    0x1820000u  // f32  [1152][64][2]

__device__ __forceinline__ unsigned short f2bf(float f) {
    union { float f; unsigned int u; } v; v.f = f;
    unsigned int u = v.u;
    return (unsigned short)((u + 0x7fffu + ((u >> 16) & 1u)) >> 16);
}

__device__ __forceinline__ float bf2f(unsigned short b) {
    union { unsigned int u; float f; } v; v.u = ((unsigned int)b) << 16;
    return v.f;
}

__device__ __forceinline__ unsigned int cvtpk(float lo, float hi) {
    unsigned int r;
    asm("v_cvt_pk_bf16_f32 %0, %1, %2" : "=v"(r) : "v"(lo), "v"(hi));
    return r;
}

// ---------------- convert / transpose pre-pass ----------------
__global__ __launch_bounds__(256)
void convert_kernel(const float* __restrict__ Q, const float* __restrict__ K,
                    const float* __restrict__ V, const float* __restrict__ Msk,
                    const float* __restrict__ Krel, char* __restrict__ ws)
{
    const int tid = threadIdx.x;
    const int bid = blockIdx.x;
    unsigned short* Qb  = (unsigned short*)(ws + OFF_QB);
    unsigned short* Kb  = (unsigned short*)(ws + OFF_KB);
    unsigned short* VTb = (unsigned short*)(ws + OFF_VTB);
    float*          pen = (float*)(ws + OFF_PEN);
    unsigned short* Krb = (unsigned short*)(ws + OFF_KREL);

    if (bid < 1024) {                       // Q -> bf16, scaled
        int base = bid * 1024 + tid * 4;
        f32x4 q4 = *(const f32x4*)(Q + base);
        s16x4 o;
        o.x = (short)f2bf(q4.x * QSCALE); o.y = (short)f2bf(q4.y * QSCALE);
        o.z = (short)f2bf(q4.z * QSCALE); o.w = (short)f2bf(q4.w * QSCALE);
        *(s16x4*)(Qb + base) = o;
    } else if (bid < 2048) {                // K -> bf16
        int base = (bid - 1024) * 1024 + tid * 4;
        f32x4 k4 = *(const f32x4*)(K + base);
        s16x4 o;
        o.x = (short)f2bf(k4.x); o.y = (short)f2bf(k4.y);
        o.z = (short)f2bf(k4.z); o.w = (short)f2bf(k4.w);
        *(s16x4*)(Kb + base) = o;
    } else if (bid < 2304) {                // V transpose (64x64 tiles) -> bf16
        __shared__ unsigned short tileT[64][72];
        int tile = bid - 2048;
        int b = tile >> 5, k0 = (tile & 31) << 6;
        #pragma unroll
        for (int rep = 0; rep < 4; ++rep) {
            int idx = tid + rep * 256;
            int kr = idx >> 4, dc0 = (idx & 15) << 2;
            f32x4 v4 = *(const f32x4*)(V + (size_t)(b * 2048 + k0 + kr) * 64 + dc0);
            tileT[dc0 + 0][kr] = f2bf(v4.x);
            tileT[dc0 + 1][kr] = f2bf(v4.y);
            tileT[dc0 + 2][kr] = f2bf(v4.z);
            tileT[dc0 + 3][kr] = f2bf(v4.w);
        }
        __syncthreads();
        #pragma unroll
        for (int rep = 0; rep < 2; ++rep) {
            int idx = tid + rep * 256;
            int d = idx >> 3, ch = idx & 7;
            *(s16x8*)(VTb + (size_t)(b * 64 + d) * 2048 + k0 + ch * 8) =
                *(const s16x8*)&tileT[d][ch * 8];
        }
    } else if (bid < 2312) {                // mask -> additive penalty (log2 dom)
        int i0 = (bid - 2304) * 2048 + tid * 8;
        f32x4 m0 = *(const f32x4*)(Msk + i0);
        f32x4 m1 = *(const f32x4*)(Msk + i0 + 4);
        f32x4 p0 = (m0 - 1.0f) * PENSCALE;
        f32x4 p1 = (m1 - 1.0f) * PENSCALE;
        *(f32x4*)(pen + i0) = p0;
        *(f32x4*)(pen + i0 + 4) = p1;
    } else {                                // Krel -> bf16, padded to 48 rows
        for (int g = tid; g < 768; g += 256) {
            int e = g * 4, row = e >> 6, col = e & 63;
            s16x4 o;
            if (row < 33) {
                f32x4 v = *(const f32x4*)(Krel + row * 64 + col);
                o.x = (short)f2bf(v.x); o.y = (short)f2bf(v.y);
                o.z = (short)f2bf(v.z); o.w = (short)f2bf(v.w);
            } else {
                o.x = 0; o.y = 0; o.z = 0; o.w = 0;
            }
            *(s16x4*)(Krb + row * 64 + col) = o;
        }
    }
}

// ---------------- main flash-attention (split-K CH=4, LPT order) ----------------
// LDS: K 8192 + VT 8192 @0; P per-wave 4x2048 @16384; drel @24576; vrel @29696
#define LDS_KVT  0
#define LDS_P    16384
#define LDS_DREL 24576
#define LDS_VREL 29696
#define LDS_TOT  34592

__device__ __forceinline__ void near_bias(f32x4& sv, const f32x4& pv, int cc,
                                          int k0, int g0, int q,
                                          const float* drel) {
#pragma unroll
    for (int r = 0; r < 4; ++r) {
        int kk = k0 + cc * 16 + 4 * g0 + r;
        int dlt = q - kk;
        int idx = dlt < 16 ? dlt : 16;
        idx = idx < 0 ? 0 : idx;
        float bb = drel[idx];
        float v = sv[r] + bb + pv[r];
        sv[r] = (dlt < 0) ? -1e30f : v;
    }
}

__global__ __launch_bounds__(256, 4)
void attn_main(const float* __restrict__ Vrel_g, float* __restrict__ Out,
               char* __restrict__ ws)
{
    __shared__ __align__(16) char lds[LDS_TOT];
    const int tid  = threadIdx.x;
    const int wv   = tid >> 6;
    const int lane = tid & 63;
    const int g0   = lane >> 4;
    const int qh   = lane & 15;

    // XCD bijection: 1152 blocks = 8 XCDs x 144; round-robin dispatch gives
    // XCD x the units of batch x only (K/V working set 1 MB -> L2-resident).
    // Within a batch, units are ordered LONGEST-FIRST (band i=7 down to 0),
    // so low blockIdx = 4-tile units: LPT scheduling without atomics.
    const int b = blockIdx.x & 7;
    const int v = blockIdx.x >> 3;
    const int u = b * UPB + v;

    int i, st;
    if      (v < 32)  { i = 7; st = 0;   }
    else if (v < 60)  { i = 6; st = 32;  }
    else if (v < 84)  { i = 5; st = 60;  }
    else if (v < 104) { i = 4; st = 84;  }
    else if (v < 120) { i = 3; st = 104; }
    else if (v < 132) { i = 2; st = 120; }
    else if (v < 140) { i = 1; st = 132; }
    else              { i = 0; st = 140; }
    const int r_   = v - st;
    const int nck  = i + 1;
    const int t    = 4 * i + r_ / nck;
    const int chunk = r_ % nck;
    const int q0   = t << 6;
    const int q0w  = q0 + wv * 16;
    const int q    = q0w + qh;
    const int ck0  = chunk * CH;
    const int ckend = min(ck0 + CH, t + 1);
    const bool is_final = (nck == 1);

    const unsigned short* Qb  = (const unsigned short*)(ws + OFF_QB);
    const unsigned short* Kb  = (const unsigned short*)(ws + OFF_KB);
    const unsigned short* VTb = (const unsigned short*)(ws + OFF_VTB);
    const float*          pen = (const float*)(ws + OFF_PEN);
    const unsigned short* Krb = (const unsigned short*)(ws + OFF_KREL);

    // Q fragments (hoisted); q-row = lane&15
    const size_t qrow = (size_t)(b * 2048 + q) * 64;
    s16x8 qf0 = *(const s16x8*)(Qb + qrow + 0 * 32 + g0 * 8);
    s16x8 qf1 = *(const s16x8*)(Qb + qrow + 1 * 32 + g0 * 8);

    // drel (relative-key dots) via MFMA: Krel rows 16..31 and 32
    {
        s16x8 a10 = *(const s16x8*)(Krb + (16 + qh) * 64 + 0 * 32 + g0 * 8);
        s16x8 a11 = *(const s16x8*)(Krb + (16 + qh) * 64 + 1 * 32 + g0 * 8);
        s16x8 a20 = *(const s16x8*)(Krb + (32 + qh) * 64 + 0 * 32 + g0 * 8);
        s16x8 a21 = *(const s16x8*)(Krb + (32 + qh) * 64 + 1 * 32 + g0 * 8);
        f32x4 z = {0.f, 0.f, 0.f, 0.f};
        f32x4 d1 = __builtin_amdgcn_mfma_f32_16x16x32_bf16(a10, qf0, z, 0, 0, 0);
        d1 = __builtin_amdgcn_mfma_f32_16x16x32_bf16(a11, qf1, d1, 0, 0, 0);
        f32x4 d2 = __builtin_amdgcn_mfma_f32_16x16x32_bf16(a20, qf0, z, 0, 0, 0);
        d2 = __builtin_amdgcn_mfma_f32_16x16x32_bf16(a21, qf1, d2, 0, 0, 0);
        float* drel = (float*)(lds + LDS_DREL) + wv * 320 + qh * 20;
        drel[4 * g0 + 0] = d1.x; drel[4 * g0 + 1] = d1.y;
        drel[4 * g0 + 2] = d1.z; drel[4 * g0 + 3] = d1.w;
        if (g0 == 0) drel[16] = d2.x;     // drel[q][32]
    }
    asm volatile("" ::: "memory");
    const float* drelT = (const float*)(lds + LDS_DREL) + wv * 320 + qh * 20;
    float bias32 = drelT[16];

    // Vrel rows 0..16 staged f32
    {
        float* vr = (float*)(lds + LDS_VREL);
        for (int ii = tid; ii < 17 * 16; ii += 256) {
            int row = ii >> 4, c4 = (ii & 15) << 2;
            *(f32x4*)(vr + row * 72 + c4) = *(const f32x4*)(Vrel_g + row * 64 + c4);
        }
    }

    f32x4 o0 = {0,0,0,0}, o1 = {0,0,0,0}, o2 = {0,0,0,0}, o3 = {0,0,0,0};
    float mprev = -1e30f, lsum = 0.f;

    char* KsL = lds + LDS_KVT;
    char* VtL = KsL + 8192;
    char* PL  = lds + LDS_P + wv * 2048;
    const int swzq = (qh & 7) << 4;
    const float* vrel = (const float*)(lds + LDS_VREL);

    // staging addresses (2 K rows + 2 VT rows per thread)
    const int idx0 = tid,        idx1 = tid + 256;
    const int row0 = idx0 >> 3,  cb0 = (idx0 & 7) << 4;
    const int row1 = idx1 >> 3,  cb1 = (idx1 & 7) << 4;
    const int sw0 = cb0 ^ ((row0 & 7) << 4);
    const int sw1 = cb1 ^ ((row1 & 7) << 4);
    const char* ksrc0 = (const char*)(Kb  + (size_t)(b * 2048 + row0) * 64) + cb0;
    const char* ksrc1 = (const char*)(Kb  + (size_t)(b * 2048 + row1) * 64) + cb1;
    const char* vsrc0 = (const char*)(VTb + (size_t)(b * 64 + row0) * 2048) + cb0;
    const char* vsrc1 = (const char*)(VTb + (size_t)(b * 64 + row1) * 2048) + cb1;

    for (int kt = ck0; kt < ckend; ++kt) {
        const int k0 = kt << 6;
        __syncthreads();   // prior tile's compute done; safe to overwrite
        // stage K + VT (bf16, 8KB each), XOR-swizzled
        *(s16x8*)(KsL + row0 * 128 + sw0) = *(const s16x8*)(ksrc0 + (size_t)kt * 8192);
        *(s16x8*)(KsL + row1 * 128 + sw1) = *(const s16x8*)(ksrc1 + (size_t)kt * 8192);
        *(s16x8*)(VtL + row0 * 128 + sw0) = *(const s16x8*)(vsrc0 + (size_t)kt * 128);
        *(s16x8*)(VtL + row1 * 128 + sw1) = *(const s16x8*)(vsrc1 + (size_t)kt * 128);
        __syncthreads();

        const int b0 = (16 * g0) ^ swzq;
        const int b1 = (64 + 16 * g0) ^ swzq;
        // ---- S^T = K_tile . Q^T ----
        f32x4 s0, s1, s2, s3;
        {
            f32x4 z = {0,0,0,0};
            s16x8 a0 = *(const s16x8*)(KsL + (0  + qh) * 128 + b0);
            s16x8 a1 = *(const s16x8*)(KsL + (0  + qh) * 128 + b1);
            s16x8 a2 = *(const s16x8*)(KsL + (16 + qh) * 128 + b0);
            s16x8 a3 = *(const s16x8*)(KsL + (16 + qh) * 128 + b1);
            s0 = __builtin_amdgcn_mfma_f32_16x16x32_bf16(a0, qf0, z, 0, 0, 0);
            s0 = __builtin_amdgcn_mfma_f32_16x16x32_bf16(a1, qf1, s0, 0, 0, 0);
            a0 = *(const s16x8*)(KsL + (32 + qh) * 128 + b0);
            a1 = *(const s16x8*)(KsL + (32 + qh) * 128 + b1);
            s1 = __builtin_amdgcn_mfma_f32_16x16x32_bf16(a2, qf0, z, 0, 0, 0);
            s1 = __builtin_amdgcn_mfma_f32_16x16x32_bf16(a3, qf1, s1, 0, 0, 0);
            a2 = *(const s16x8*)(KsL + (48 + qh) * 128 + b0);
            a3 = *(const s16x8*)(KsL + (48 + qh) * 128 + b1);
            s2 = __builtin_amdgcn_mfma_f32_16x16x32_bf16(a0, qf0, z, 0, 0, 0);
            s2 = __builtin_amdgcn_mfma_f32_16x16x32_bf16(a1, qf1, s2, 0, 0, 0);
            s3 = __builtin_amdgcn_mfma_f32_16x16x32_bf16(a2, qf0, z, 0, 0, 0);
            s3 = __builtin_amdgcn_mfma_f32_16x16x32_bf16(a3, qf1, s3, 0, 0, 0);
        }
        // ---- bias + mask penalty (pen from L2) ----
        const float* penb = pen + b * 2048 + k0 + 4 * g0;
        f32x4 pn0 = *(const f32x4*)(penb + 0);
        f32x4 pn1 = *(const f32x4*)(penb + 16);
        f32x4 pn2 = *(const f32x4*)(penb + 32);
        f32x4 pn3 = *(const f32x4*)(penb + 48);
        const bool near = (k0 + 79 >= q0w);
        if (!near) {
            s0 += pn0 + bias32; s1 += pn1 + bias32;
            s2 += pn2 + bias32; s3 += pn3 + bias32;
        } else {
            near_bias(s0, pn0, 0, k0, g0, q, drelT);
            near_bias(s1, pn1, 1, k0, g0, q, drelT);
            near_bias(s2, pn2, 2, k0, g0, q, drelT);
            near_bias(s3, pn3, 3, k0, g0, q, drelT);
        }
        // ---- online softmax, log2 domain ----
        float mt = fmaxf(fmaxf(fmaxf(s0.x, s0.y), fmaxf(s0.z, s0.w)),
                  fmaxf(fmaxf(fmaxf(s1.x, s1.y), fmaxf(s1.z, s1.w)),
                  fmaxf(fmaxf(fmaxf(s2.x, s2.y), fmaxf(s2.z, s2.w)),
                        fmaxf(fmaxf(s3.x, s3.y), fmaxf(s3.z, s3.w)))));
        mt = fmaxf(mt, __shfl_xor(mt, 16));
        mt = fmaxf(mt, __shfl_xor(mt, 32));
        float mnew = fmaxf(mprev, mt);
        float fsc = __builtin_amdgcn_exp2f(mprev - mnew);
        s0.x = __builtin_amdgcn_exp2f(s0.x - mnew); s0.y = __builtin_amdgcn_exp2f(s0.y - mnew);
        s0.z = __builtin_amdgcn_exp2f(s0.z - mnew); s0.w = __builtin_amdgcn_exp2f(s0.w - mnew);
        s1.x = __builtin_amdgcn_exp2f(s1.x - mnew); s1.y = __builtin_amdgcn_exp2f(s1.y - mnew);
        s1.z = __builtin_amdgcn_exp2f(s1.z - mnew); s1.w = __builtin_amdgcn_exp2f(s1.w - mnew);
        s2.x = __builtin_amdgcn_exp2f(s2.x - mnew); s2.y = __builtin_amdgcn_exp2f(s2.y - mnew);
        s2.z = __builtin_amdgcn_exp2f(s2.z - mnew); s2.w = __builtin_amdgcn_exp2f(s2.w - mnew);
        s3.x = __builtin_amdgcn_exp2f(s3.x - mnew); s3.y = __builtin_amdgcn_exp2f(s3.y - mnew);
        s3.z = __builtin_amdgcn_exp2f(s3.z - mnew); s3.w = __builtin_amdgcn_exp2f(s3.w - mnew);
        float rs = (s0.x + s0.y + s0.z + s0.w) + (s1.x + s1.y + s1.z + s1.w)
                 + (s2.x + s2.y + s2.z + s2.w) + (s3.x + s3.y + s3.z + s3.w);
        rs += __shfl_xor(rs, 16);
        rs += __shfl_xor(rs, 32);
        lsum = lsum * fsc + rs;
        mprev = mnew;
        o0 *= fsc; o1 *= fsc; o2 *= fsc; o3 *= fsc;

        // ---- P -> bf16 (cvt_pk) -> per-wave LDS (swizzled) ----
        {
            u32x2 pk;
            pk.x = cvtpk(s0.x, s0.y); pk.y = cvtpk(s0.z, s0.w);
            *(u32x2*)(PL + qh * 128 + ((0  + 8 * g0) ^ swzq)) = pk;
            pk.x = cvtpk(s1.x, s1.y); pk.y = cvtpk(s1.z, s1.w);
            *(u32x2*)(PL + qh * 128 + ((32 + 8 * g0) ^ swzq)) = pk;
            pk.x = cvtpk(s2.x, s2.y); pk.y = cvtpk(s2.z, s2.w);
            *(u32x2*)(PL + qh * 128 + ((64 + 8 * g0) ^ swzq)) = pk;
            pk.x = cvtpk(s3.x, s3.y); pk.y = cvtpk(s3.z, s3.w);
            *(u32x2*)(PL + qh * 128 + ((96 + 8 * g0) ^ swzq)) = pk;
        }
        asm volatile("" ::: "memory");
        // ---- O^T += V^T . P^T ----
        {
            s16x8 bP0 = *(const s16x8*)(PL + qh * 128 + b0);
            s16x8 bP1 = *(const s16x8*)(PL + qh * 128 + b1);
            asm volatile("" ::: "memory");
            s16x8 v0 = *(const s16x8*)(VtL + (0  + qh) * 128 + b0);
            s16x8 v1 = *(const s16x8*)(VtL + (0  + qh) * 128 + b1);
            s16x8 v2 = *(const s16x8*)(VtL + (16 + qh) * 128 + b0);
            s16x8 v3 = *(const s16x8*)(VtL + (16 + qh) * 128 + b1);
            o0 = __builtin_amdgcn_mfma_f32_16x16x32_bf16(v0, bP0, o0, 0, 0, 0);
            o0 = __builtin_amdgcn_mfma_f32_16x16x32_bf16(v1, bP1, o0, 0, 0, 0);
            v0 = *(const s16x8*)(VtL + (32 + qh) * 128 + b0);
            v1 = *(const s16x8*)(VtL + (32 + qh) * 128 + b1);
            o1 = __builtin_amdgcn_mfma_f32_16x16x32_bf16(v2, bP0, o1, 0, 0, 0);
            o1 = __builtin_amdgcn_mfma_f32_16x16x32_bf16(v3, bP1, o1, 0, 0, 0);
            v2 = *(const s16x8*)(VtL + (48 + qh) * 128 + b0);
            v3 = *(const s16x8*)(VtL + (48 + qh) * 128 + b1);
            o2 = __builtin_amdgcn_mfma_f32_16x16x32_bf16(v0, bP0, o2, 0, 0, 0);
            o2 = __builtin_amdgcn_mfma_f32_16x16x32_bf16(v1, bP1, o2, 0, 0, 0);
            o3 = __builtin_amdgcn_mfma_f32_16x16x32_bf16(v2, bP0, o3, 0, 0, 0);
            o3 = __builtin_amdgcn_mfma_f32_16x16x32_bf16(v3, bP1, o3, 0, 0, 0);
        }
        // ---- near-diagonal relative-value recombination (all d) ----
        if (near) {
            const int kql = q - k0;
            #pragma unroll
            for (int dlt = 0; dlt <= 16; ++dlt) {
                int kkl = kql - dlt;
                if (kkl >= 0 && kkl < 64) {
                    float p = bf2f(*(const unsigned short*)
                                   (PL + qh * 128 + ((2 * kkl) ^ swzq)));
                    const float* vrow = vrel + (16 - dlt) * 72 + 4 * g0;
                    o0 += p * *(const f32x4*)(vrow + 0);
                    o1 += p * *(const f32x4*)(vrow + 16);
                    o2 += p * *(const f32x4*)(vrow + 32);
                    o3 += p * *(const f32x4*)(vrow + 48);
                }
            }
        }
    }

    // ---- epilogue ----
    if (is_final) {
        float inv = 1.f / lsum;
        float* op = Out + (size_t)(b * 2048 + q) * 64 + 4 * g0;
        *(f32x4*)(op + 0)  = o0 * inv;
        *(f32x4*)(op + 16) = o1 * inv;
        *(f32x4*)(op + 32) = o2 * inv;
        *(f32x4*)(op + 48) = o3 * inv;
    } else {
        float* op = (float*)(ws + OFF_OPART) + (size_t)u * 4096 + (wv * 16 + qh) * 64 + 4 * g0;
        *(f32x4*)(op + 0)  = o0;
        *(f32x4*)(op + 16) = o1;
        *(f32x4*)(op + 32) = o2;
        *(f32x4*)(op + 48) = o3;
        if (g0 == 0) {
            float* ml = (float*)(ws + OFF_ML) + (size_t)u * 128 + (wv * 16 + qh) * 2;
            ml[0] = mprev; ml[1] = lsum;
        }
    }
}

// ---------------- split-K combine ----------------
__global__ __launch_bounds__(256)
void combine_kernel(float* __restrict__ Out, const char* __restrict__ ws)
{
    // 224 blocks = 8 batches x 28 q-tiles (t=4..31)
    int bid = blockIdx.x;
    int b = bid / 28;
    int t = 4 + bid % 28;
    int nck = (t + 4) >> 2;            // ceil((t+1)/4)
    int i = nck - 1;
    const int startTab[8] = {140, 132, 120, 104, 84, 60, 32, 0};
    int v0 = startTab[i] + (t - 4 * i) * nck;
    int ubase = b * UPB + v0;
    int tid = threadIdx.x;
    int qloc = tid >> 2;
    int d0 = (tid & 3) << 4;
    const float* mlb = (const float*)(ws + OFF_ML);
    const float* opb = (const float*)(ws + OFF_OPART);

    float m[8], l[8];
    float M = -1e30f;
    #pragma unroll
    for (int ic = 0; ic < 8; ++ic) {
        if (ic < nck) {
            const float* ml = mlb + (size_t)(ubase + ic) * 128 + qloc * 2;
            m[ic] = ml[0]; l[ic] = ml[1];
            M = fmaxf(M, m[ic]);
        }
    }
    float L = 0.f;
    float coef[8];
    #pragma unroll
    for (int ic = 0; ic < 8; ++ic) {
        if (ic < nck) { coef[ic] = __builtin_amdgcn_exp2f(m[ic] - M); L += l[ic] * coef[ic]; }
    }
    f32x4 a0 = {0,0,0,0}, a1 = {0,0,0,0}, a2 = {0,0,0,0}, a3 = {0,0,0,0};
    #pragma unroll
    for (int ic = 0; ic < 8; ++ic) {
        if (ic < nck) {
            const float* op = opb + (size_t)(ubase + ic) * 4096 + qloc * 64 + d0;
            a0 += coef[ic] * *(const f32x4*)(op + 0);
            a1 += coef[ic] * *(const f32x4*)(op + 4);
            a2 += coef[ic] * *(const f32x4*)(op + 8);
            a3 += coef[ic] * *(const f32x4*)(op + 12);
        }
    }
    float inv = 1.f / L;
    float* oo = Out + (size_t)(b * 2048 + t * 64 + qloc) * 64 + d0;
    *(f32x4*)(oo + 0)  = a0 * inv;
    *(f32x4*)(oo + 4)  = a1 * inv;
    *(f32x4*)(oo + 8)  = a2 * inv;
    *(f32x4*)(oo + 12) = a3 * inv;
}

extern "C" void kernel_launch(void* const* d_in, const int* in_sizes, int n_in,
                              void* d_out, int out_size, void* d_ws, size_t ws_size,
                              hipStream_t stream) {
    (void)in_sizes; (void)n_in; (void)out_size; (void)ws_size;
    const float* Q    = (const float*)d_in[0];
    const float* K    = (const float*)d_in[1];
    const float* V    = (const float*)d_in[2];
    const float* Msk  = (const float*)d_in[3];
    const float* Krel = (const float*)d_in[4];
    const float* Vrel = (const float*)d_in[5];
    float* Out = (float*)d_out;
    char* ws = (char*)d_ws;

    convert_kernel<<<2313, 256, 0, stream>>>(Q, K, V, Msk, Krel, ws);
    attn_main<<<NUNIT, 256, 0, stream>>>(Vrel, Out, ws);
    combine_kernel<<<224, 256, 0, stream>>>(Out, ws);
}